// Round 3
// baseline (376.830 us; speedup 1.0000x reference)
//
#include <hip/hip_runtime.h>
#include <math.h>

#define NN 325
#define BT 96
#define RS 0.35355339059327373f  // 1/sqrt(8)

__device__ __forceinline__ float gelu_f(float x) {
    return 0.5f * x * (1.0f + erff(x * 0.70710678118654752f));
}

// ---------------------------------------------------------------------------
// Kernel 0: pack adj into transposed bitmasks: packedT[w*NN + n] holds bits
// for columns m = 32w..32w+31 of row n. Bits for m >= NN are 0.
// ---------------------------------------------------------------------------
__global__ void pack_adj_kernel(const int* __restrict__ adj,
                                unsigned int* __restrict__ packedT)
{
    int idx = blockIdx.x * 256 + threadIdx.x;
    if (idx >= 11 * NN) return;
    int w = idx / NN, n = idx - w * NN;
    unsigned int bits = 0u;
    #pragma unroll 8
    for (int j = 0; j < 32; ++j) {
        int m = w * 32 + j;
        if (m < NN && adj[n * NN + m] > 0) bits |= (1u << j);
    }
    packedT[w * NN + n] = bits;
}

// ---------------------------------------------------------------------------
// Kernel 1: x = concat(X, STE) [.,128]; q/k/v = gelu(x @ W.T + b)  [.,64]
// (unchanged from R2 — known-good; optimize next round with real numbers)
// ---------------------------------------------------------------------------
__device__ __forceinline__ void qkv_phase(
    const float* __restrict__ W, const float* __restrict__ b,
    float* __restrict__ outp, const float* xs, float* ws,
    int tid, int bt, int r0)
{
    __syncthreads();
    for (int idx = tid; idx < 64 * 128; idx += 256) {
        int c = idx >> 7, i = idx & 127;
        ws[i * 68 + c] = W[idx];   // transposed store
    }
    __syncthreads();

    const int c4 = (tid & 15) * 4;
    const int rg = tid >> 4;

    float4 bias = *(const float4*)(b + c4);
    float4 acc0 = bias, acc1 = bias;
    const float* x0p = xs + rg * 132;
    const float* x1p = xs + (rg + 16) * 132;
    #pragma unroll 4
    for (int i = 0; i < 128; ++i) {
        float xa = x0p[i], xb = x1p[i];
        float4 w4 = *(const float4*)&ws[i * 68 + c4];
        acc0.x = fmaf(xa, w4.x, acc0.x);
        acc0.y = fmaf(xa, w4.y, acc0.y);
        acc0.z = fmaf(xa, w4.z, acc0.z);
        acc0.w = fmaf(xa, w4.w, acc0.w);
        acc1.x = fmaf(xb, w4.x, acc1.x);
        acc1.y = fmaf(xb, w4.y, acc1.y);
        acc1.z = fmaf(xb, w4.z, acc1.z);
        acc1.w = fmaf(xb, w4.w, acc1.w);
    }
    int n0 = r0 + rg, n1 = r0 + rg + 16;
    if (n0 < NN) {
        float4 g;
        g.x = gelu_f(acc0.x); g.y = gelu_f(acc0.y);
        g.z = gelu_f(acc0.z); g.w = gelu_f(acc0.w);
        *(float4*)&outp[(bt * NN + n0) * 64 + c4] = g;
    }
    if (n1 < NN) {
        float4 g;
        g.x = gelu_f(acc1.x); g.y = gelu_f(acc1.y);
        g.z = gelu_f(acc1.z); g.w = gelu_f(acc1.w);
        *(float4*)&outp[(bt * NN + n1) * 64 + c4] = g;
    }
}

__global__ __launch_bounds__(256) void qkv_kernel(
    const float* __restrict__ X, const float* __restrict__ STE,
    const float* __restrict__ W7, const float* __restrict__ b7,
    const float* __restrict__ W8, const float* __restrict__ b8,
    const float* __restrict__ W9, const float* __restrict__ b9,
    float* __restrict__ q, float* __restrict__ k, float* __restrict__ v)
{
    __shared__ float xs[32 * 132];
    __shared__ float ws[128 * 68];
    const int tid = threadIdx.x;
    const int bt  = blockIdx.y;
    const int r0  = blockIdx.x * 32;

    for (int idx = tid; idx < 32 * 128; idx += 256) {
        int r = idx >> 7, i = idx & 127;
        int n = r0 + r;
        float val = 0.0f;
        if (n < NN) {
            val = (i < 64) ? X[(bt * NN + n) * 64 + i]
                           : STE[(bt * NN + n) * 64 + (i - 64)];
        }
        xs[r * 132 + i] = val;
    }

    qkv_phase(W7, b7, q, xs, ws, tid, bt, r0);
    qkv_phase(W8, b8, k, xs, ws, tid, bt, r0);
    qkv_phase(W9, b9, v, xs, ws, tid, bt, r0);
}

// ---------------------------------------------------------------------------
// Kernel 2: attention, lane-per-row. Each thread owns rows tid (+ tid+256).
// K/V read with wave-uniform addresses (scalar-load path, no LDS); adjacency
// as packed bits (LDS-staged); softmax without max-subtraction (p = exp(s)
// for allowed, 0 for masked — mathematically identical, overflow-safe here).
// ---------------------------------------------------------------------------
__device__ __forceinline__ float dot8(const float* qr, float4 a, float4 b) {
    float s = qr[0] * a.x;
    s = fmaf(qr[1], a.y, s); s = fmaf(qr[2], a.z, s); s = fmaf(qr[3], a.w, s);
    s = fmaf(qr[4], b.x, s); s = fmaf(qr[5], b.y, s);
    s = fmaf(qr[6], b.z, s); s = fmaf(qr[7], b.w, s);
    return s;
}

__device__ __forceinline__ void pv8(float* acc, float p, float4 a, float4 b) {
    acc[0] = fmaf(p, a.x, acc[0]); acc[1] = fmaf(p, a.y, acc[1]);
    acc[2] = fmaf(p, a.z, acc[2]); acc[3] = fmaf(p, a.w, acc[3]);
    acc[4] = fmaf(p, b.x, acc[4]); acc[5] = fmaf(p, b.y, acc[5]);
    acc[6] = fmaf(p, b.z, acc[6]); acc[7] = fmaf(p, b.w, acc[7]);
}

__global__ __launch_bounds__(256) void attn_kernel(
    const float* __restrict__ q, const float* __restrict__ k,
    const float* __restrict__ v, const unsigned int* __restrict__ packedT,
    float* __restrict__ ao)
{
    __shared__ unsigned int Ms[11 * NN];   // 14.3 KB
    const int tid = threadIdx.x;
    const int h = blockIdx.x, bt = blockIdx.y;
    const int base = (bt * NN) * 64 + h * 8;

    for (int idx = tid; idx < 11 * NN; idx += 256)
        Ms[idx] = packedT[idx];
    __syncthreads();

    const int n0 = tid;                 // < 325 always
    const int n1 = tid + 256;
    const bool has1 = (n1 < NN);

    float q0[8], q1[8];
    {
        float4 a = *(const float4*)(q + base + n0 * 64);
        float4 b = *(const float4*)(q + base + n0 * 64 + 4);
        q0[0] = a.x * RS; q0[1] = a.y * RS; q0[2] = a.z * RS; q0[3] = a.w * RS;
        q0[4] = b.x * RS; q0[5] = b.y * RS; q0[6] = b.z * RS; q0[7] = b.w * RS;
    }
    #pragma unroll
    for (int d = 0; d < 8; ++d) q1[d] = 0.f;
    if (has1) {
        float4 a = *(const float4*)(q + base + n1 * 64);
        float4 b = *(const float4*)(q + base + n1 * 64 + 4);
        q1[0] = a.x * RS; q1[1] = a.y * RS; q1[2] = a.z * RS; q1[3] = a.w * RS;
        q1[4] = b.x * RS; q1[5] = b.y * RS; q1[6] = b.z * RS; q1[7] = b.w * RS;
    }

    float acc0[8], acc1[8];
    #pragma unroll
    for (int d = 0; d < 8; ++d) { acc0[d] = 0.f; acc1[d] = 0.f; }
    float sum0 = 0.f, sum1 = 0.f;

    const float* kb = k + base;
    const float* vb = v + base;

    for (int w = 0; w < 11; ++w) {
        unsigned int mw0 = Ms[w * NN + n0];
        unsigned int mw1 = has1 ? Ms[w * NN + n1] : 0u;
        #pragma unroll
        for (int b = 0; b < 32; ++b) {
            const int m = w * 32 + b;
            const int mc = (m < NN) ? m : 0;   // uniform; avoids OOB/NaN garbage
            float4 ka = *(const float4*)(kb + mc * 64);
            float4 kc = *(const float4*)(kb + mc * 64 + 4);
            float4 va = *(const float4*)(vb + mc * 64);
            float4 vc = *(const float4*)(vb + mc * 64 + 4);

            float s0 = dot8(q0, ka, kc);
            float p0 = ((mw0 >> b) & 1u) ? __expf(s0) : 0.f;
            sum0 += p0;
            pv8(acc0, p0, va, vc);

            if (has1) {
                float s1 = dot8(q1, ka, kc);
                float p1 = ((mw1 >> b) & 1u) ? __expf(s1) : 0.f;
                sum1 += p1;
                pv8(acc1, p1, va, vc);
            }
        }
    }

    {
        float inv = 1.0f / sum0;
        float4 o0, o1;
        o0.x = acc0[0] * inv; o0.y = acc0[1] * inv;
        o0.z = acc0[2] * inv; o0.w = acc0[3] * inv;
        o1.x = acc0[4] * inv; o1.y = acc0[5] * inv;
        o1.z = acc0[6] * inv; o1.w = acc0[7] * inv;
        *(float4*)(ao + base + n0 * 64)     = o0;
        *(float4*)(ao + base + n0 * 64 + 4) = o1;
    }
    if (has1) {
        float inv = 1.0f / sum1;
        float4 o0, o1;
        o0.x = acc1[0] * inv; o0.y = acc1[1] * inv;
        o0.z = acc1[2] * inv; o0.w = acc1[3] * inv;
        o1.x = acc1[4] * inv; o1.y = acc1[5] * inv;
        o1.z = acc1[6] * inv; o1.w = acc1[7] * inv;
        *(float4*)(ao + base + n1 * 64)     = o0;
        *(float4*)(ao + base + n1 * 64 + 4) = o1;
    }
}

// ---------------------------------------------------------------------------
// Kernel 3: out = gelu(ao @ W10.T + b10) @ W11.T + b11.  32 rows/block,
// transposed aT/hT tiles (stride 36, float4-aligned) -> per-i reads are
// 1 b32 (weight, 2-way=free) + 2 broadcast b128. 8 rows/thread.
// ---------------------------------------------------------------------------
__global__ __launch_bounds__(256) void proj_kernel(
    const float* __restrict__ ao,
    const float* __restrict__ W10, const float* __restrict__ b10,
    const float* __restrict__ W11, const float* __restrict__ b11,
    float* __restrict__ out)
{
    __shared__ float W10s[64 * 65];
    __shared__ float W11s[64 * 65];
    __shared__ float aT[64 * 36];
    __shared__ float hT[64 * 36];
    const int tid = threadIdx.x;
    const int rowbase = blockIdx.x * 32;

    for (int idx = tid; idx < 4096; idx += 256) {
        int c = idx >> 6, i = idx & 63;
        W10s[i * 65 + c] = W10[idx];
        W11s[i * 65 + c] = W11[idx];
    }
    for (int idx = tid; idx < 2048; idx += 256) {
        int r = idx >> 6, i = idx & 63;
        aT[i * 36 + r] = ao[(rowbase + r) * 64 + i];
    }
    __syncthreads();

    const int c = tid & 63, rg = tid >> 6;  // rg uniform per wave
    const int r0 = rg * 8;
    float acc[8];
    float bb = b10[c];
    #pragma unroll
    for (int rr = 0; rr < 8; ++rr) acc[rr] = bb;
    #pragma unroll 4
    for (int i = 0; i < 64; ++i) {
        float w = W10s[i * 65 + c];
        float4 a0 = *(const float4*)&aT[i * 36 + r0];
        float4 a1 = *(const float4*)&aT[i * 36 + r0 + 4];
        acc[0] = fmaf(a0.x, w, acc[0]); acc[1] = fmaf(a0.y, w, acc[1]);
        acc[2] = fmaf(a0.z, w, acc[2]); acc[3] = fmaf(a0.w, w, acc[3]);
        acc[4] = fmaf(a1.x, w, acc[4]); acc[5] = fmaf(a1.y, w, acc[5]);
        acc[6] = fmaf(a1.z, w, acc[6]); acc[7] = fmaf(a1.w, w, acc[7]);
    }
    #pragma unroll
    for (int rr = 0; rr < 8; ++rr)
        hT[c * 36 + r0 + rr] = gelu_f(acc[rr]);
    __syncthreads();

    float bb2 = b11[c];
    #pragma unroll
    for (int rr = 0; rr < 8; ++rr) acc[rr] = bb2;
    #pragma unroll 4
    for (int i = 0; i < 64; ++i) {
        float w = W11s[i * 65 + c];
        float4 h0 = *(const float4*)&hT[i * 36 + r0];
        float4 h1 = *(const float4*)&hT[i * 36 + r0 + 4];
        acc[0] = fmaf(h0.x, w, acc[0]); acc[1] = fmaf(h0.y, w, acc[1]);
        acc[2] = fmaf(h0.z, w, acc[2]); acc[3] = fmaf(h0.w, w, acc[3]);
        acc[4] = fmaf(h1.x, w, acc[4]); acc[5] = fmaf(h1.y, w, acc[5]);
        acc[6] = fmaf(h1.z, w, acc[6]); acc[7] = fmaf(h1.w, w, acc[7]);
    }
    #pragma unroll
    for (int rr = 0; rr < 8; ++rr)
        out[(rowbase + r0 + rr) * 64 + c] = acc[rr];
}

extern "C" void kernel_launch(void* const* d_in, const int* in_sizes, int n_in,
                              void* d_out, int out_size, void* d_ws, size_t ws_size,
                              hipStream_t stream) {
    const float* X   = (const float*)d_in[0];
    const float* STE = (const float*)d_in[1];
    const int*   adj = (const int*)d_in[2];
    const float* W7  = (const float*)d_in[3];
    const float* b7  = (const float*)d_in[4];
    const float* W8  = (const float*)d_in[5];
    const float* b8  = (const float*)d_in[6];
    const float* W9  = (const float*)d_in[7];
    const float* b9  = (const float*)d_in[8];
    const float* W10 = (const float*)d_in[9];
    const float* b10 = (const float*)d_in[10];
    const float* W11 = (const float*)d_in[11];
    const float* b11 = (const float*)d_in[12];

    float* ws = (float*)d_ws;
    const long S = (long)BT * NN * 64;  // 1,996,800 floats
    float* qb = ws;
    float* kb = ws + S;
    float* vb = ws + 2 * S;
    float* ab = ws + 3 * S;
    unsigned int* pk = (unsigned int*)(ws + 4 * S);  // 11*NN words

    pack_adj_kernel<<<(11 * NN + 255) / 256, 256, 0, stream>>>(adj, pk);
    qkv_kernel<<<dim3(11, BT), 256, 0, stream>>>(X, STE, W7, b7, W8, b8, W9, b9,
                                                 qb, kb, vb);
    attn_kernel<<<dim3(8, BT), 256, 0, stream>>>(qb, kb, vb, pk, ab);
    proj_kernel<<<dim3(975), 256, 0, stream>>>(ab, W10, b10, W11, b11,
                                               (float*)d_out);
}

// Round 4
// 231.277 us; speedup vs baseline: 1.6293x; 1.6293x over previous
//
#include <hip/hip_runtime.h>
#include <math.h>

#define NN 325
#define BT 96
#define RS 0.35355339059327373f  // 1/sqrt(8)
// fold softmax scale and log2(e) into q: exp(s/sqrt8) == exp2(s * SCL)
#define SCL (0.35355339059327373f * 1.4426950408889634f)

__device__ __forceinline__ float gelu_f(float x) {
    return 0.5f * x * (1.0f + erff(x * 0.70710678118654752f));
}

// ---------------------------------------------------------------------------
// Kernel 0: pack adj into transposed bitmasks: packedT[w*NN + n] holds bits
// for columns m = 32w..32w+31 of row n. Bits for m >= NN are 0.
// ---------------------------------------------------------------------------
__global__ void pack_adj_kernel(const int* __restrict__ adj,
                                unsigned int* __restrict__ packedT)
{
    int idx = blockIdx.x * 256 + threadIdx.x;
    if (idx >= 11 * NN) return;
    int w = idx / NN, n = idx - w * NN;
    unsigned int bits = 0u;
    #pragma unroll 8
    for (int j = 0; j < 32; ++j) {
        int m = w * 32 + j;
        if (m < NN && adj[n * NN + m] > 0) bits |= (1u << j);
    }
    packedT[w * NN + n] = bits;
}

// ---------------------------------------------------------------------------
// Kernel 1: x = concat(X, STE) [.,128]; q/k/v = gelu(x @ W.T + b)  [.,64]
// (unchanged from R2/R3 — optimize once it's the top dispatch)
// ---------------------------------------------------------------------------
__device__ __forceinline__ void qkv_phase(
    const float* __restrict__ W, const float* __restrict__ b,
    float* __restrict__ outp, const float* xs, float* ws,
    int tid, int bt, int r0)
{
    __syncthreads();
    for (int idx = tid; idx < 64 * 128; idx += 256) {
        int c = idx >> 7, i = idx & 127;
        ws[i * 68 + c] = W[idx];   // transposed store
    }
    __syncthreads();

    const int c4 = (tid & 15) * 4;
    const int rg = tid >> 4;

    float4 bias = *(const float4*)(b + c4);
    float4 acc0 = bias, acc1 = bias;
    const float* x0p = xs + rg * 132;
    const float* x1p = xs + (rg + 16) * 132;
    #pragma unroll 4
    for (int i = 0; i < 128; ++i) {
        float xa = x0p[i], xb = x1p[i];
        float4 w4 = *(const float4*)&ws[i * 68 + c4];
        acc0.x = fmaf(xa, w4.x, acc0.x);
        acc0.y = fmaf(xa, w4.y, acc0.y);
        acc0.z = fmaf(xa, w4.z, acc0.z);
        acc0.w = fmaf(xa, w4.w, acc0.w);
        acc1.x = fmaf(xb, w4.x, acc1.x);
        acc1.y = fmaf(xb, w4.y, acc1.y);
        acc1.z = fmaf(xb, w4.z, acc1.z);
        acc1.w = fmaf(xb, w4.w, acc1.w);
    }
    int n0 = r0 + rg, n1 = r0 + rg + 16;
    if (n0 < NN) {
        float4 g;
        g.x = gelu_f(acc0.x); g.y = gelu_f(acc0.y);
        g.z = gelu_f(acc0.z); g.w = gelu_f(acc0.w);
        *(float4*)&outp[(bt * NN + n0) * 64 + c4] = g;
    }
    if (n1 < NN) {
        float4 g;
        g.x = gelu_f(acc1.x); g.y = gelu_f(acc1.y);
        g.z = gelu_f(acc1.z); g.w = gelu_f(acc1.w);
        *(float4*)&outp[(bt * NN + n1) * 64 + c4] = g;
    }
}

__global__ __launch_bounds__(256) void qkv_kernel(
    const float* __restrict__ X, const float* __restrict__ STE,
    const float* __restrict__ W7, const float* __restrict__ b7,
    const float* __restrict__ W8, const float* __restrict__ b8,
    const float* __restrict__ W9, const float* __restrict__ b9,
    float* __restrict__ q, float* __restrict__ k, float* __restrict__ v)
{
    __shared__ float xs[32 * 132];
    __shared__ float ws[128 * 68];
    const int tid = threadIdx.x;
    const int bt  = blockIdx.y;
    const int r0  = blockIdx.x * 32;

    for (int idx = tid; idx < 32 * 128; idx += 256) {
        int r = idx >> 7, i = idx & 127;
        int n = r0 + r;
        float val = 0.0f;
        if (n < NN) {
            val = (i < 64) ? X[(bt * NN + n) * 64 + i]
                           : STE[(bt * NN + n) * 64 + (i - 64)];
        }
        xs[r * 132 + i] = val;
    }

    qkv_phase(W7, b7, q, xs, ws, tid, bt, r0);
    qkv_phase(W8, b8, k, xs, ws, tid, bt, r0);
    qkv_phase(W9, b9, v, xs, ws, tid, bt, r0);
}

// ---------------------------------------------------------------------------
// Kernel 2: attention. Lane = query row (<=1 row/lane via 2 row-halves per
// (bt,h)); K/V interleaved in LDS kv[m][16], read via broadcast ds_read_b128
// at wave-uniform addresses; softmax in exp2 domain, no max-subtraction
// (p = 0 exactly for masked); mask bits prefetched one w ahead.
// ---------------------------------------------------------------------------
__device__ __forceinline__ float dot8(const float* qr, float4 a, float4 b) {
    float s = qr[0] * a.x;
    s = fmaf(qr[1], a.y, s); s = fmaf(qr[2], a.z, s); s = fmaf(qr[3], a.w, s);
    s = fmaf(qr[4], b.x, s); s = fmaf(qr[5], b.y, s);
    s = fmaf(qr[6], b.z, s); s = fmaf(qr[7], b.w, s);
    return s;
}

__device__ __forceinline__ void pv8(float* acc, float p, float4 a, float4 b) {
    acc[0] = fmaf(p, a.x, acc[0]); acc[1] = fmaf(p, a.y, acc[1]);
    acc[2] = fmaf(p, a.z, acc[2]); acc[3] = fmaf(p, a.w, acc[3]);
    acc[4] = fmaf(p, b.x, acc[4]); acc[5] = fmaf(p, b.y, acc[5]);
    acc[6] = fmaf(p, b.z, acc[6]); acc[7] = fmaf(p, b.w, acc[7]);
}

__global__ __launch_bounds__(192) void attn_kernel(
    const float* __restrict__ q, const float* __restrict__ k,
    const float* __restrict__ v, const unsigned int* __restrict__ packedT,
    float* __restrict__ ao)
{
    __shared__ float kv[352 * 16];   // 22.5 KB: [m][k0..k7, v0..v7], zero-pad
    const int tid = threadIdx.x;
    const int h = blockIdx.x, bt = blockIdx.y, half = blockIdx.z;
    const int base = (bt * NN) * 64 + h * 8;
    const int rowbase = half * 163;
    const int nrows = half ? 162 : 163;

    // stage K/V (float4 granularity), zero-fill m in [325,352)
    for (int qd = tid; qd < 352 * 4; qd += 192) {
        int m = qd >> 2, part = qd & 3;
        float4 val = make_float4(0.f, 0.f, 0.f, 0.f);
        if (m < NN) {
            const float* src = (part < 2) ? (k + base + m * 64 + part * 4)
                                          : (v + base + m * 64 + (part - 2) * 4);
            val = *(const float4*)src;
        }
        *(float4*)&kv[m * 16 + part * 4] = val;
    }
    __syncthreads();

    const int n = rowbase + ((tid < nrows) ? tid : 0);

    float qs[8];
    {
        float4 a = *(const float4*)(q + base + n * 64);
        float4 b = *(const float4*)(q + base + n * 64 + 4);
        qs[0] = a.x * SCL; qs[1] = a.y * SCL; qs[2] = a.z * SCL; qs[3] = a.w * SCL;
        qs[4] = b.x * SCL; qs[5] = b.y * SCL; qs[6] = b.z * SCL; qs[7] = b.w * SCL;
    }

    float acc[8] = {0.f,0.f,0.f,0.f,0.f,0.f,0.f,0.f};
    float sum = 0.f;

    unsigned int mw = packedT[n];   // w = 0
    for (int w = 0; w < 11; ++w) {
        unsigned int mw_next = (w < 10) ? packedT[(w + 1) * NN + n] : 0u;
        const float* kvw = kv + w * 512;
        #pragma unroll
        for (int b = 0; b < 32; ++b) {
            float4 ka  = *(const float4*)(kvw + b * 16);
            float4 kb4 = *(const float4*)(kvw + b * 16 + 4);
            float4 va  = *(const float4*)(kvw + b * 16 + 8);
            float4 vb4 = *(const float4*)(kvw + b * 16 + 12);
            float s = dot8(qs, ka, kb4);
            float e = __builtin_amdgcn_exp2f(s);
            float p = (mw & (1u << b)) ? e : 0.f;
            sum += p;
            pv8(acc, p, va, vb4);
        }
        mw = mw_next;
    }

    if (tid < nrows) {
        float inv = 1.0f / sum;
        float4 o0, o1;
        o0.x = acc[0] * inv; o0.y = acc[1] * inv;
        o0.z = acc[2] * inv; o0.w = acc[3] * inv;
        o1.x = acc[4] * inv; o1.y = acc[5] * inv;
        o1.z = acc[6] * inv; o1.w = acc[7] * inv;
        *(float4*)(ao + base + n * 64)     = o0;
        *(float4*)(ao + base + n * 64 + 4) = o1;
    }
}

// ---------------------------------------------------------------------------
// Kernel 3: out = gelu(ao @ W10.T + b10) @ W11.T + b11.  32 rows/block,
// transposed aT/hT tiles (stride 36, float4-aligned). 8 rows/thread.
// ---------------------------------------------------------------------------
__global__ __launch_bounds__(256) void proj_kernel(
    const float* __restrict__ ao,
    const float* __restrict__ W10, const float* __restrict__ b10,
    const float* __restrict__ W11, const float* __restrict__ b11,
    float* __restrict__ out)
{
    __shared__ float W10s[64 * 65];
    __shared__ float W11s[64 * 65];
    __shared__ float aT[64 * 36];
    __shared__ float hT[64 * 36];
    const int tid = threadIdx.x;
    const int rowbase = blockIdx.x * 32;

    for (int idx = tid; idx < 4096; idx += 256) {
        int c = idx >> 6, i = idx & 63;
        W10s[i * 65 + c] = W10[idx];
        W11s[i * 65 + c] = W11[idx];
    }
    for (int idx = tid; idx < 2048; idx += 256) {
        int r = idx >> 6, i = idx & 63;
        aT[i * 36 + r] = ao[(rowbase + r) * 64 + i];
    }
    __syncthreads();

    const int c = tid & 63, rg = tid >> 6;
    const int r0 = rg * 8;
    float acc[8];
    float bb = b10[c];
    #pragma unroll
    for (int rr = 0; rr < 8; ++rr) acc[rr] = bb;
    #pragma unroll 4
    for (int i = 0; i < 64; ++i) {
        float w = W10s[i * 65 + c];
        float4 a0 = *(const float4*)&aT[i * 36 + r0];
        float4 a1 = *(const float4*)&aT[i * 36 + r0 + 4];
        acc[0] = fmaf(a0.x, w, acc[0]); acc[1] = fmaf(a0.y, w, acc[1]);
        acc[2] = fmaf(a0.z, w, acc[2]); acc[3] = fmaf(a0.w, w, acc[3]);
        acc[4] = fmaf(a1.x, w, acc[4]); acc[5] = fmaf(a1.y, w, acc[5]);
        acc[6] = fmaf(a1.z, w, acc[6]); acc[7] = fmaf(a1.w, w, acc[7]);
    }
    #pragma unroll
    for (int rr = 0; rr < 8; ++rr)
        hT[c * 36 + r0 + rr] = gelu_f(acc[rr]);
    __syncthreads();

    float bb2 = b11[c];
    #pragma unroll
    for (int rr = 0; rr < 8; ++rr) acc[rr] = bb2;
    #pragma unroll 4
    for (int i = 0; i < 64; ++i) {
        float w = W11s[i * 65 + c];
        float4 h0 = *(const float4*)&hT[i * 36 + r0];
        float4 h1 = *(const float4*)&hT[i * 36 + r0 + 4];
        acc[0] = fmaf(h0.x, w, acc[0]); acc[1] = fmaf(h0.y, w, acc[1]);
        acc[2] = fmaf(h0.z, w, acc[2]); acc[3] = fmaf(h0.w, w, acc[3]);
        acc[4] = fmaf(h1.x, w, acc[4]); acc[5] = fmaf(h1.y, w, acc[5]);
        acc[6] = fmaf(h1.z, w, acc[6]); acc[7] = fmaf(h1.w, w, acc[7]);
    }
    #pragma unroll
    for (int rr = 0; rr < 8; ++rr)
        out[(rowbase + r0 + rr) * 64 + c] = acc[rr];
}

extern "C" void kernel_launch(void* const* d_in, const int* in_sizes, int n_in,
                              void* d_out, int out_size, void* d_ws, size_t ws_size,
                              hipStream_t stream) {
    const float* X   = (const float*)d_in[0];
    const float* STE = (const float*)d_in[1];
    const int*   adj = (const int*)d_in[2];
    const float* W7  = (const float*)d_in[3];
    const float* b7  = (const float*)d_in[4];
    const float* W8  = (const float*)d_in[5];
    const float* b8  = (const float*)d_in[6];
    const float* W9  = (const float*)d_in[7];
    const float* b9  = (const float*)d_in[8];
    const float* W10 = (const float*)d_in[9];
    const float* b10 = (const float*)d_in[10];
    const float* W11 = (const float*)d_in[11];
    const float* b11 = (const float*)d_in[12];

    float* ws = (float*)d_ws;
    const long S = (long)BT * NN * 64;  // 1,996,800 floats
    float* qb = ws;
    float* kb = ws + S;
    float* vb = ws + 2 * S;
    float* ab = ws + 3 * S;
    unsigned int* pk = (unsigned int*)(ws + 4 * S);  // 11*NN words

    pack_adj_kernel<<<(11 * NN + 255) / 256, 256, 0, stream>>>(adj, pk);
    qkv_kernel<<<dim3(11, BT), 256, 0, stream>>>(X, STE, W7, b7, W8, b8, W9, b9,
                                                 qb, kb, vb);
    attn_kernel<<<dim3(8, BT, 2), 192, 0, stream>>>(qb, kb, vb, pk, ab);
    proj_kernel<<<dim3(975), 256, 0, stream>>>(ab, W10, b10, W11, b11,
                                               (float*)d_out);
}